// Round 1
// baseline (1417.117 us; speedup 1.0000x reference)
//
#include <hip/hip_runtime.h>

#define B_ 512
#define T_ 512

typedef __bf16 bf16x8 __attribute__((ext_vector_type(8)));
typedef float  f32x4  __attribute__((ext_vector_type(4)));
using u16 = unsigned short;

__device__ __forceinline__ float fast_rcp(float x) { return __builtin_amdgcn_rcpf(x); }
__device__ __forceinline__ float sigf(float x)     { return fast_rcp(1.0f + __expf(-x)); }
__device__ __forceinline__ float tanhfast(float x) { return 1.0f - 2.0f * fast_rcp(__expf(2.0f * x) + 1.0f); }

// fp32 -> bf16 RNE
__device__ __forceinline__ u16 f2bf(float f) {
    unsigned u = __float_as_uint(f);
    u += 0x7FFFu + ((u >> 16) & 1u);
    return (u16)(u >> 16);
}

// Light barrier: orders LDS only; global stores stay in flight across ticks.
// Field-verified correct in r5.
__device__ __forceinline__ void lbar() {
    asm volatile("s_waitcnt lgkmcnt(0)\n\ts_barrier" ::: "memory");
}

// DPP quad-perm move (VALU pipe). 0xB1 = quad_perm[1,0,3,2], 0x4E = quad_perm[2,3,0,1].
// Field-verified correct in r5.
template<int CTRL>
__device__ __forceinline__ float dppq(float v) {
    int r = __builtin_amdgcn_update_dpp(0, __float_as_int(v), CTRL, 0xF, 0xF, true);
    return __int_as_float(r);
}

// One LSTM layer's per-wave state + step. All loops compile-time unrolled so
// WB/bias/cst stay in registers (rule #20). DSS = downstream LDS row stride
// (u16 units); GOUT = last layer writes f32 global instead of LDS.
template<int D, int H, int TPW, int DSS, bool GOUT>
struct LL {
    static constexpr int K    = D + H;
    static constexpr int KF   = (K + 31) / 32;
    static constexpr int SSTR = KF * 32 + 8;   // u16: 16B-aligned rows, bank-spread

    bf16x8 WB[TPW][KF];
    float  bias[TPW][4];
    float  cst[TPW];
    int    tile[TPW];   // wave-uniform (from readfirstlane'd wave id)
    bool   tv[TPW];     // tile valid (wave-uniform)

    __device__ __forceinline__ void init(const float* __restrict__ Wih,
                                         const float* __restrict__ Whh,
                                         const float* __restrict__ bih,
                                         const float* __restrict__ bhh,
                                         int lane) {
        const int q = lane >> 4, cc = lane & 15;
#pragma unroll
        for (int tp = 0; tp < TPW; ++tp) {
            cst[tp] = 0.0f;
            if (tv[tp]) {
                const int nglob = tile[tp] * 16 + cc;     // gate-interleaved col n=4u+g
                const int u = nglob >> 2, g = nglob & 3;
                const int row = g * H + u;
#pragma unroll
                for (int kf = 0; kf < KF; ++kf) {
                    bf16x8 w;
#pragma unroll
                    for (int jj = 0; jj < 8; ++jj) {
                        const int k = kf * 32 + q * 8 + jj;
                        float v = 0.0f;
                        if (k < D)      v = Wih[row * D + k];
                        else if (k < K) v = Whh[row * H + (k - D)];
                        w[jj] = (__bf16)v;
                    }
                    WB[tp][kf] = w;
                }
                const int uu = tile[tp] * 4 + (cc >> 2);
#pragma unroll
                for (int g2 = 0; g2 < 4; ++g2)
                    bias[tp][g2] = bih[g2 * H + uu] + bhh[g2 * H + uu];
            } else {
                // masked tile: zero weights so unguarded MFMA is harmless
#pragma unroll
                for (int kf = 0; kf < KF; ++kf)
#pragma unroll
                    for (int jj = 0; jj < 8; ++jj) WB[tp][kf][jj] = (__bf16)0.0f;
#pragma unroll
                for (int g2 = 0; g2 < 4; ++g2) bias[tp][g2] = 0.0f;
            }
        }
    }

    // cur: this layer's input buffer (x | h_{t-1}); own: buffer receiving h_t
    // (h-region, cols D..D+H); down: next layer's buffer receiving h_t as its
    // x (cols 0..H). For GOUT: gbase = &out[(b0*T + t)*H], hnb = hn row base
    // (non-null only at t==T-1).
    __device__ __forceinline__ void step(const u16* __restrict__ cur,
                                         u16* __restrict__ own,
                                         u16* __restrict__ down,
                                         float* __restrict__ gbase,
                                         float* __restrict__ hnb,
                                         int lane) {
        const int q = lane >> 4, cc = lane & 15;
        bf16x8 A[KF];
#pragma unroll
        for (int kf = 0; kf < KF; ++kf)
            A[kf] = *(const bf16x8*)&cur[cc * SSTR + kf * 32 + q * 8];

        f32x4 acc[TPW];
#pragma unroll
        for (int tp = 0; tp < TPW; ++tp) acc[tp] = f32x4{0.f, 0.f, 0.f, 0.f};
#pragma unroll
        for (int kf = 0; kf < KF; ++kf)
#pragma unroll
            for (int tp = 0; tp < TPW; ++tp)
                acc[tp] = __builtin_amdgcn_mfma_f32_16x16x32_bf16(A[kf], WB[tp][kf], acc[tp], 0, 0, 0);

        const bool bA = lane & 1, bB = lane & 2;
        const int  rr = 4 * q + (lane & 3);               // batch row after transpose
#pragma unroll
        for (int tp = 0; tp < TPW; ++tp) {
            if (tv[tp]) {
                float v0 = acc[tp][0], v1 = acc[tp][1], v2 = acc[tp][2], v3 = acc[tp][3];
                float s;
                s = dppq<0xB1>(bA ? v0 : v1); if (bA) v0 = s; else v1 = s;
                s = dppq<0xB1>(bA ? v2 : v3); if (bA) v2 = s; else v3 = s;
                s = dppq<0x4E>(bB ? v0 : v2); if (bB) v0 = s; else v2 = s;
                s = dppq<0x4E>(bB ? v1 : v3); if (bB) v1 = s; else v3 = s;

                const float gi = sigf(v0 + bias[tp][0]);
                const float gf = sigf(v1 + bias[tp][1]);
                const float gg = tanhfast(v2 + bias[tp][2]);
                const float go = sigf(v3 + bias[tp][3]);
                const float c  = gf * cst[tp] + gi * gg;
                cst[tp] = c;
                const float h  = go * tanhfast(c);

                const int u = tile[tp] * 4 + (cc >> 2);
                own[rr * SSTR + D + u] = f2bf(h);         // own-h feedback
                if constexpr (GOUT) {
                    gbase[rr * (T_ * H) + u] = h;         // dec_out, f32
                    if (hnb) hnb[rr * H + u] = h;         // h_n at t=T-1
                } else {
                    down[rr * DSS + u] = f2bf(h);         // next layer's x
                }
            }
        }
    }
};

// Fused 3-layer pipelined LSTM. One block = 16 batch rows through all layers.
// Tick tau: L1 step tau, L2 step tau-1, L3 step tau-2 (514 ticks vs 1536
// barrier-steps for the 3-kernel version). Parity rule: layer at step s reads
// buf[s&1], writes own-h to buf[(s+1)&1], downstream-h to buf_next[s&1] —
// intra-tick reads/writes always on opposite parities, so one lbar per tick.
constexpr int S1 = 104, S2 = 104, S3 = 200;
constexpr int B1W = 16 * S1, B2W = 16 * S2, B3W = 16 * S3;
constexpr int SMW = 2 * (B1W + B2W + B3W);   // 13056 u16 = 26112 B

__global__ __launch_bounds__(512)
void lstm3_fused(const float* __restrict__ z,
                 const float* __restrict__ Wih1, const float* __restrict__ Whh1,
                 const float* __restrict__ bih1, const float* __restrict__ bhh1,
                 const float* __restrict__ Wih2, const float* __restrict__ Whh2,
                 const float* __restrict__ bih2, const float* __restrict__ bhh2,
                 const float* __restrict__ Wih3, const float* __restrict__ Whh3,
                 const float* __restrict__ bih3, const float* __restrict__ bhh3,
                 float* __restrict__ out, float* __restrict__ hn)
{
    __shared__ u16 smem[SMW];
    u16* b1 = smem;
    u16* b2 = smem + 2 * B1W;
    u16* b3 = b2 + 2 * B2W;

    const int tid  = threadIdx.x;
    const int lane = tid & 63;
    const int wvu  = __builtin_amdgcn_readfirstlane(tid >> 6);  // SGPR wave id
    const int b0   = blockIdx.x * 16;

    static_assert(LL<64, 32, 1, S2, false>::SSTR == S1, "S1");
    static_assert(LL<32, 48, 2, S3, false>::SSTR == S2, "S2");
    static_assert(LL<48, 128, 4, 0, true>::SSTR == S3, "S3");

    LL<64, 32, 1, S2, false> l1;   // D=64  H=32  : 8 tiles  -> 1/wave
    LL<32, 48, 2, S3, false> l2;   // D=32  H=48  : 12 tiles -> 2/wave (tile1 on wv<4)
    LL<48, 128, 4, 0, true>  l3;   // D=48  H=128 : 32 tiles -> 4/wave

    l1.tile[0] = wvu;      l1.tv[0] = true;
    l2.tile[0] = wvu;      l2.tv[0] = true;
    l2.tile[1] = 8 + wvu;  l2.tv[1] = (wvu < 4);
#pragma unroll
    for (int tp = 0; tp < 4; ++tp) { l3.tile[tp] = wvu + 8 * tp; l3.tv[tp] = true; }

    l1.init(Wih1, Whh1, bih1, bhh1, lane);
    l2.init(Wih2, Whh2, bih2, bhh2, lane);
    l3.init(Wih3, Whh3, bih3, bhh3, lane);

    // zero all buffers (incl. K..KF*32 padding — must stay 0), then stage x_0
    for (int i = tid; i < SMW; i += 512) smem[i] = 0;
    lbar();

    const int xr = tid >> 5, xp = tid & 31;          // 512 thr = 16 rows x 32 dwords
    int xoff = (b0 + xr) * (T_ * 32) + xp;           // float2 index; fits int
    {
        const float2 f = ((const float2*)z)[xoff];
        const unsigned pk = (unsigned)f2bf(f.x) | ((unsigned)f2bf(f.y) << 16);
        *(unsigned*)&b1[xr * S1 + 2 * xp] = pk;      // parity 0 = step-0 cur
    }
    xoff += 32;
    lbar();

    for (int tick = 0; tick < T_ + 2; ++tick) {
        const int qq = tick & 1;
        u16* b1c = b1 + qq * B1W;        u16* b1n = b1 + (qq ^ 1) * B1W;
        u16* b2c = b2 + (qq ^ 1) * B2W;  u16* b2n = b2 + qq * B2W;
        u16* b3c = b3 + qq * B3W;        u16* b3n = b3 + (qq ^ 1) * B3W;

        // prefetch x_{tick+1} early; ds_write at tick end (vmcnt waited there)
        unsigned pk = 0;
        const bool hasx = (tick + 1 < T_);
        if (hasx) {
            const float2 f = ((const float2*)z)[xoff];
            pk = (unsigned)f2bf(f.x) | ((unsigned)f2bf(f.y) << 16);
        }
        xoff += 32;

        if (tick < T_)
            l1.step(b1c, b1n, b2n, nullptr, nullptr, lane);
        if (tick >= 1 && tick <= T_)
            l2.step(b2c, b2n, b3n, nullptr, nullptr, lane);
        if (tick >= 2) {
            float* gbase = out + ((size_t)b0 * T_ + (tick - 2)) * 128;
            float* hnb   = (tick == T_ + 1) ? (hn + b0 * 128) : nullptr;
            l3.step(b3c, b3n, nullptr, gbase, hnb, lane);
        }

        if (hasx) *(unsigned*)&b1n[xr * S1 + 2 * xp] = pk;
        lbar();
    }
}

extern "C" void kernel_launch(void* const* d_in, const int* in_sizes, int n_in,
                              void* d_out, int out_size, void* d_ws, size_t ws_size,
                              hipStream_t stream)
{
    (void)in_sizes; (void)n_in; (void)out_size; (void)d_ws; (void)ws_size;
    const float* z    = (const float*)d_in[0];
    const float* Wih1 = (const float*)d_in[1];
    const float* Whh1 = (const float*)d_in[2];
    const float* bih1 = (const float*)d_in[3];
    const float* bhh1 = (const float*)d_in[4];
    const float* Wih2 = (const float*)d_in[5];
    const float* Whh2 = (const float*)d_in[6];
    const float* bih2 = (const float*)d_in[7];
    const float* bhh2 = (const float*)d_in[8];
    const float* Wih3 = (const float*)d_in[9];
    const float* Whh3 = (const float*)d_in[10];
    const float* bih3 = (const float*)d_in[11];
    const float* bhh3 = (const float*)d_in[12];

    float* out = (float*)d_out;                   // [B,T,128]
    float* hn  = out + (size_t)B_ * T_ * 128;     // [1,B,128]

    hipLaunchKernelGGL(lstm3_fused, dim3(32), dim3(512), 0, stream,
                       z, Wih1, Whh1, bih1, bhh1,
                       Wih2, Whh2, bih2, bhh2,
                       Wih3, Whh3, bih3, bhh3, out, hn);
}